// Round 9
// baseline (10285.865 us; speedup 1.0000x reference)
//
#include <hip/hip_runtime.h>
#include <stdint.h>
#include <stddef.h>

#define B_ 16
#define T_ 4096
#define D_ 256
#define H_ 512
#define G3_ 1536

// ws layout
#define OFF_IG   ((size_t)0)                       // igates f16: 65536*1536*2 = 201326592
#define OFF_WT   ((size_t)201326592)               // W_ih^T packed float4: 256*1536*4 = 1572864
#define OFF_MB   ((size_t)202899456)               // MALL mailboxes: 2*16*8*512*4 = 524288
#define WS_NEED  ((size_t)203423744)
// L2 mailbox copy reuses the WT region (dead after ig_kernel): 524288 B <= 1572864 B
#define OFF_MBL  OFF_WT

#define PAR_STRIDE ((size_t)B_ * 8 * 512)           // words per parity buffer

typedef _Float16 h2_t __attribute__((ext_vector_type(2)));

#if defined(__has_builtin)
#if __has_builtin(__builtin_amdgcn_fdot2)
#define HAVE_FDOT2 1
#endif
#endif

__device__ __forceinline__ float fdot2f(uint32_t w, uint32_t h, float acc) {
  union { uint32_t u; h2_t v; } a, b;
  a.u = w; b.u = h;
#ifdef HAVE_FDOT2
  return __builtin_amdgcn_fdot2(a.v, b.v, acc, false);
#else
  return fmaf((float)a.v.x, (float)b.v.x, fmaf((float)a.v.y, (float)b.v.y, acc));
#endif
}

__device__ __forceinline__ uint32_t packh2(float a, float b) {
  union { h2_t v; uint32_t u; } x;
  x.v.x = (_Float16)a; x.v.y = (_Float16)b;
  return x.u;
}

__device__ __forceinline__ uint32_t f16bits(float a) {
  union { _Float16 h; uint16_t u; } x;
  x.h = (_Float16)a;
  return (uint32_t)x.u;
}

__device__ __forceinline__ float h2f(uint16_t u) {
  union { _Float16 h; uint16_t u; } x;
  x.u = u;
  return (float)x.h;
}

__device__ __forceinline__ float sigmoidf_(float x) {
  return 1.0f / (1.0f + __expf(-x));
}

__device__ __forceinline__ float tanhf_(float x) {
  x = fminf(fmaxf(x, -15.0f), 15.0f);
  float e = __expf(-2.0f * x);
  return (1.0f - e) / (1.0f + e);
}

// ---------------- Kernel 1: transpose+pack W_ih into [d/4][g] float4 ----------------
__global__ void __launch_bounds__(256) wt_kernel(const float* __restrict__ W, float4* __restrict__ Wt4) {
  int idx = blockIdx.x * 256 + threadIdx.x;   // over 1536*64
  if (idx >= G3_ * 64) return;
  int g = idx % G3_;
  int d4 = idx / G3_;
  float4 v = *(const float4*)(W + (size_t)g * D_ + 4 * d4);
  Wt4[(size_t)d4 * G3_ + g] = v;
}

// ---------------- Kernel 2: igates = xs @ W_ih^T + b  -> f16 ----------------
__global__ void __launch_bounds__(256) ig_kernel(const float* __restrict__ xs,
                                                 const float* __restrict__ Wt,
                                                 const float* __restrict__ bias,
                                                 _Float16* __restrict__ ig) {
  __shared__ float xls[16 * 256];
  const int m0 = blockIdx.x * 16;
  const int tid = threadIdx.x;

  const float4* xsrc = (const float4*)(xs + (size_t)m0 * D_);
  float4* xdst = (float4*)xls;
#pragma unroll
  for (int k = 0; k < 4; ++k) xdst[tid + 256 * k] = xsrc[tid + 256 * k];
  __syncthreads();

  float acc[6][16];
#pragma unroll
  for (int k = 0; k < 6; ++k)
#pragma unroll
    for (int m = 0; m < 16; ++m) acc[k][m] = 0.0f;

  const float4* Wt4 = (const float4*)Wt;
  const float4* lds4 = (const float4*)xls;

  for (int d4 = 0; d4 < 64; ++d4) {
    float4 w[6];
#pragma unroll
    for (int k = 0; k < 6; ++k) w[k] = Wt4[(size_t)d4 * G3_ + tid + 256 * k];
#pragma unroll
    for (int m = 0; m < 16; ++m) {
      float4 xv = lds4[m * 64 + d4];
#pragma unroll
      for (int k = 0; k < 6; ++k) {
        acc[k][m] = fmaf(w[k].x, xv.x, acc[k][m]);
        acc[k][m] = fmaf(w[k].y, xv.y, acc[k][m]);
        acc[k][m] = fmaf(w[k].z, xv.z, acc[k][m]);
        acc[k][m] = fmaf(w[k].w, xv.w, acc[k][m]);
      }
    }
  }

#pragma unroll
  for (int k = 0; k < 6; ++k) {
    float bb = bias[tid + 256 * k];
#pragma unroll
    for (int m = 0; m < 16; ++m) {
      ig[(size_t)(m0 + m) * G3_ + tid + 256 * k] = (_Float16)(acc[k][m] + bb);
    }
  }
}

// ---------------- Kernel 3: persistent recurrence ----------------
// 256 WGs x 256 threads, 1 WG/CU. Remap wg -> (b,s): x=wg&7, y=wg>>3,
// b = x + 8*(y>>4), s = y&15. Under round-robin XCD placement (xcd = wg%8)
// all 16 WGs of batch b land on XCD (b&7) -> batch exchange is XCD-local.
// Thread: q = tid&7 (K-slice of 64), c = tid>>3, j = s*32 + c.
// Weights: rows {j, j+512, j+1024} x K[q*64,+64) = 96 packed f16-pair VGPRs.
// Exchange (tagged words (tag<<16)|f16(h), 8 copies/batch, dbuf by parity):
//  - producer DUAL-publishes: plain store -> L2 copy (lands in XCD L2, L1 is
//    write-through) AND agent-scope atomic store -> MALL copy (always valid).
//  - consumer tries 8 rounds of sc0-only loads on the L2 copy (XCD-local,
//    ~200cy RT); on failure falls back THIS STEP to the proven sc1/MALL poll;
//    8 consecutive failed steps -> sticky demote to MALL-only.
//  Correctness never depends on the fast path: tag-gated (within-replay stale
//  => older tag; cross-replay stale => bit-identical value by determinism).
// Detection -> LDS redistribute (padded [8][36]) -> ONE barrier/step.
// Slot-overwrite race-free: publish is ordered after the barrier, and tag t+2
// is written only after the producer detected t+1 from ALL columns, which
// happens-after every consumer's barrier(t) (hence after their reads of t).
__global__ void __launch_bounds__(256, 1) rec_kernel(const _Float16* __restrict__ ig,
                                                     const float* __restrict__ Whh,
                                                     const float* __restrict__ bn,
                                                     uint32_t* __restrict__ mbM,
                                                     uint32_t* __restrict__ mbL,
                                                     float* __restrict__ out) {
  const int tid = threadIdx.x;
  const int wg = blockIdx.x;       // 0..255
  const int x = wg & 7;
  const int y = wg >> 3;           // 0..31
  const int b = x + 8 * (y >> 4);  // 0..15 (16 WGs of b share XCD x under %8 rr)
  const int s = y & 15;            // 0..15
  const int q = tid & 7;           // K-slice
  const int c = tid >> 3;          // 0..31
  const int j = s * 32 + c;        // 0..511

  // ---- load + pack weights into registers (96 dwords) ----
  uint32_t wr[32], wz[32], wn[32];
  {
    const float4* s0 = (const float4*)(Whh + (size_t)j * H_ + q * 64);
    const float4* s1 = (const float4*)(Whh + (size_t)(j + H_) * H_ + q * 64);
    const float4* s2 = (const float4*)(Whh + (size_t)(j + 2 * H_) * H_ + q * 64);
#pragma unroll
    for (int i = 0; i < 16; ++i) {
      float4 v0 = s0[i]; wr[2 * i] = packh2(v0.x, v0.y); wr[2 * i + 1] = packh2(v0.z, v0.w);
      float4 v1 = s1[i]; wz[2 * i] = packh2(v1.x, v1.y); wz[2 * i + 1] = packh2(v1.z, v1.w);
      float4 v2 = s2[i]; wn[2 * i] = packh2(v2.x, v2.y); wn[2 * i + 1] = packh2(v2.z, v2.w);
    }
  }
  const float bnj = bn[j];

  // double-buffered padded LDS h-pairs: [parity][8 regions][32 + 4 pad]
  __shared__ uint32_t hl[2][8][36];

  // mailbox addresses (same layout in both copies)
  const size_t boxoff = ((size_t)b * 8 + (s >> 1)) * 512 + 2 * tid;  // my 2 poll words
  const size_t puboff = ((size_t)b * 8 + q) * 512 + j;               // copy q, word j
  uint32_t* mypollL = mbL + boxoff;
  uint32_t* mypollM = mbM + boxoff;
  uint32_t* mypubL  = mbL + puboff;
  uint32_t* mypubM  = mbM + puboff;

  const uint16_t* ig16 = (const uint16_t*)ig;
  size_t igbase = (size_t)b * T_ * G3_;

  // ig pipeline: cur(t), nxt(t+1) preloaded; fut(t+2) issued post-detection
  uint16_t cr = ig16[igbase + j];
  uint16_t cz = ig16[igbase + j + H_];
  uint16_t cn = ig16[igbase + j + 2 * H_];
  uint16_t nr = ig16[igbase + G3_ + j];
  uint16_t nz = ig16[igbase + G3_ + j + H_];
  uint16_t nn2 = ig16[igbase + G3_ + j + 2 * H_];

  float hprev = 0.0f;
  bool fastok = true;
  int fail_streak = 0;

  for (int t = 0; t < T_; ++t) {
    uint16_t fr = 0, fz = 0, fn = 0;

    if (t > 0) {
      const uint32_t hi = (uint32_t)t << 16;
      const size_t poff = (size_t)(t & 1) * PAR_STRIDE;
      uint32_t a0 = 0, a1 = 0;
      bool ok = false;

      if (fastok) {
        // ---- fast: XCD-local L2 poll (sc0-only), bounded budget ----
        uint32_t* pl = mypollL + poff;
        for (int r2 = 0; r2 < 8; ++r2) {
          unsigned long long vv;
          asm volatile("global_load_dwordx2 %0, %1, off sc0\n\ts_waitcnt vmcnt(0)"
                       : "=v"(vv) : "v"(pl) : "memory");
          __builtin_amdgcn_sched_barrier(0);
          a0 = (uint32_t)vv;
          a1 = (uint32_t)(vv >> 32);
          if ((((a0 ^ hi) | (a1 ^ hi)) >> 16) == 0u) { ok = true; break; }
        }
        if (ok) fail_streak = 0;
        else if (++fail_streak >= 8) fastok = false;   // sticky demote
      }

      if (!ok) {
        // ---- reliable: MALL poll (agent-scope sc1), R8-proven ----
        uint32_t* pm = mypollM + poff;
        int it = 0;
        for (;;) {
          unsigned long long vv;
          asm volatile("global_load_dwordx2 %0, %1, off sc1\n\ts_waitcnt vmcnt(0)"
                       : "=v"(vv) : "v"(pm) : "memory");
          __builtin_amdgcn_sched_barrier(0);
          a0 = (uint32_t)vv;
          a1 = (uint32_t)(vv >> 32);
          if ((((a0 ^ hi) | (a1 ^ hi)) >> 16) == 0u) break;
          if (++it > (1 << 20)) { a0 = a1 = 0x7C00u; break; }  // visible poison, no hang
        }
      }

      // stage pair into LDS: slot tid -> region tid>>5, offset tid&31
      hl[t & 1][tid >> 5][tid & 31] = (a0 & 0xFFFFu) | (a1 << 16);

      // issue t+2 ig prefetch now (post-detection: polls never drain a fresh load)
      if (t + 2 < T_) {
        const size_t fb = igbase + 2 * (size_t)G3_;
        fr = ig16[fb + j];
        fz = ig16[fb + j + H_];
        fn = ig16[fb + j + 2 * H_];
      }
    } else {
      const size_t fb = igbase + 2 * (size_t)G3_;
      fr = ig16[fb + j];
      fz = ig16[fb + j + H_];
      fn = ig16[fb + j + 2 * H_];
    }

    __syncthreads();   // single barrier per step (double-buffered hl)

    float ar = 0.0f, az = 0.0f, an = 0.0f;
    if (t > 0) {
      // ---- dot: 3 gates x 32 fdot2, 2 chains per gate; conflict-free b128 ----
      const uint4* hq = (const uint4*)hl[t & 1][q];
      uint4 hv[8];
#pragma unroll
      for (int i = 0; i < 8; ++i) hv[i] = hq[i];
      float ar0 = 0.0f, az0 = 0.0f, an0 = 0.0f;
      float ar1 = 0.0f, az1 = 0.0f, an1 = 0.0f;
#pragma unroll
      for (int i = 0; i < 4; ++i) {
        ar0 = fdot2f(wr[4 * i + 0], hv[i].x, ar0); az0 = fdot2f(wz[4 * i + 0], hv[i].x, az0); an0 = fdot2f(wn[4 * i + 0], hv[i].x, an0);
        ar0 = fdot2f(wr[4 * i + 1], hv[i].y, ar0); az0 = fdot2f(wz[4 * i + 1], hv[i].y, az0); an0 = fdot2f(wn[4 * i + 1], hv[i].y, an0);
        ar0 = fdot2f(wr[4 * i + 2], hv[i].z, ar0); az0 = fdot2f(wz[4 * i + 2], hv[i].z, az0); an0 = fdot2f(wn[4 * i + 2], hv[i].z, an0);
        ar0 = fdot2f(wr[4 * i + 3], hv[i].w, ar0); az0 = fdot2f(wz[4 * i + 3], hv[i].w, az0); an0 = fdot2f(wn[4 * i + 3], hv[i].w, an0);
      }
#pragma unroll
      for (int i = 4; i < 8; ++i) {
        ar1 = fdot2f(wr[4 * i + 0], hv[i].x, ar1); az1 = fdot2f(wz[4 * i + 0], hv[i].x, az1); an1 = fdot2f(wn[4 * i + 0], hv[i].x, an1);
        ar1 = fdot2f(wr[4 * i + 1], hv[i].y, ar1); az1 = fdot2f(wz[4 * i + 1], hv[i].y, az1); an1 = fdot2f(wn[4 * i + 1], hv[i].y, an1);
        ar1 = fdot2f(wr[4 * i + 2], hv[i].z, ar1); az1 = fdot2f(wz[4 * i + 2], hv[i].z, az1); an1 = fdot2f(wn[4 * i + 2], hv[i].z, an1);
        ar1 = fdot2f(wr[4 * i + 3], hv[i].w, ar1); az1 = fdot2f(wz[4 * i + 3], hv[i].w, az1); an1 = fdot2f(wn[4 * i + 3], hv[i].w, an1);
      }
      ar = ar0 + ar1; az = az0 + az1; an = an0 + an1;
      // reduce across the 8 K-slice lanes (lanes 8c..8c+7)
      ar += __shfl_xor(ar, 1); ar += __shfl_xor(ar, 2); ar += __shfl_xor(ar, 4);
      az += __shfl_xor(az, 1); az += __shfl_xor(az, 2); az += __shfl_xor(az, 4);
      an += __shfl_xor(an, 1); an += __shfl_xor(an, 2); an += __shfl_xor(an, 4);
    }

    // ---- gates (redundant on all 8 q-lanes of a column) ----
    const float igr = h2f(cr), igz = h2f(cz), ign = h2f(cn);
    const float r = sigmoidf_(igr + ar);
    const float z = sigmoidf_(igz + az);
    const float n = tanhf_(ign + r * (an + bnj));
    const float hnew = n + z * (hprev - n);
    hprev = hnew;

    // ---- dual publish: plain -> L2 copy, agent atomic -> MALL copy ----
    const uint32_t wv = ((uint32_t)(t + 1) << 16) | f16bits(hnew);
    const size_t noff = (size_t)((t + 1) & 1) * PAR_STRIDE;
    asm volatile("global_store_dword %0, %1, off" :: "v"(mypubL + noff), "v"(wv) : "memory");
    __hip_atomic_store(mypubM + noff, wv, __ATOMIC_RELAXED, __HIP_MEMORY_SCOPE_AGENT);

    if (q == 0) {
      out[((size_t)b * T_ + t) * H_ + j] = hnew;
    }

    // rotate ig pipeline
    cr = nr; cz = nz; cn = nn2;
    nr = fr; nz = fz; nn2 = fn;
    igbase += G3_;
  }
}

// ---------------- Fallback: naive (only if ws too small) ----------------
__global__ void __launch_bounds__(512) naive_kernel(const float* __restrict__ xs,
                                                    const float* __restrict__ Wih,
                                                    const float* __restrict__ Whh,
                                                    const float* __restrict__ bias,
                                                    const float* __restrict__ bn,
                                                    float* __restrict__ out) {
  const int b = blockIdx.x;
  const int j = threadIdx.x;
  __shared__ float h[H_];
  __shared__ float xr[D_];
  h[j] = 0.0f;
  __syncthreads();
  for (int t = 0; t < T_; ++t) {
    if (j < D_) xr[j] = xs[((size_t)b * T_ + t) * D_ + j];
    __syncthreads();
    float a[2];
#pragma unroll
    for (int g = 0; g < 2; ++g) {
      const int row = j + g * H_;
      float ssum = bias[row];
      const float* wi = Wih + (size_t)row * D_;
      for (int d = 0; d < D_; ++d) ssum = fmaf(wi[d], xr[d], ssum);
      const float* wh = Whh + (size_t)row * H_;
      for (int kk = 0; kk < H_; ++kk) ssum = fmaf(wh[kk], h[kk], ssum);
      a[g] = ssum;
    }
    const float r = sigmoidf_(a[0]);
    const float z = sigmoidf_(a[1]);
    float i_n = bias[j + 2 * H_];
    {
      const float* wi = Wih + (size_t)(j + 2 * H_) * D_;
      for (int d = 0; d < D_; ++d) i_n = fmaf(wi[d], xr[d], i_n);
    }
    float h_n = 0.0f;
    {
      const float* wh = Whh + (size_t)(j + 2 * H_) * H_;
      for (int kk = 0; kk < H_; ++kk) h_n = fmaf(wh[kk], h[kk], h_n);
    }
    const float nn = tanhf_(i_n + r * (h_n + bn[j]));
    const float hnew = nn + z * (h[j] - nn);
    __syncthreads();
    h[j] = hnew;
    out[((size_t)b * T_ + t) * H_ + j] = hnew;
  }
}

extern "C" void kernel_launch(void* const* d_in, const int* in_sizes, int n_in,
                              void* d_out, int out_size, void* d_ws, size_t ws_size,
                              hipStream_t stream) {
  const float* xs  = (const float*)d_in[0];
  const float* Wih = (const float*)d_in[1];
  const float* Whh = (const float*)d_in[2];
  const float* bia = (const float*)d_in[3];
  const float* bnp = (const float*)d_in[4];
  float* out = (float*)d_out;

  if (ws_size >= WS_NEED) {
    char* ws = (char*)d_ws;
    _Float16* igp = (_Float16*)(ws + OFF_IG);
    float* wtp = (float*)(ws + OFF_WT);
    uint32_t* mbM = (uint32_t*)(ws + OFF_MB);
    uint32_t* mbL = (uint32_t*)(ws + OFF_MBL);   // aliases WT region (dead after ig)

    // zero MALL mailboxes (stale-tag hygiene across graph replays)
    hipMemsetAsync(mbM, 0, 2 * PAR_STRIDE * sizeof(uint32_t), stream);

    wt_kernel<<<dim3(384), dim3(256), 0, stream>>>(Wih, (float4*)wtp);
    ig_kernel<<<dim3((B_ * T_) / 16), dim3(256), 0, stream>>>(xs, wtp, bia, igp);

    // WT region is dead now; zero the L2 mailbox copy living inside it
    hipMemsetAsync(mbL, 0, 2 * PAR_STRIDE * sizeof(uint32_t), stream);

    rec_kernel<<<dim3(256), dim3(256), 0, stream>>>(igp, Whh, bnp, mbM, mbL, out);
  } else {
    naive_kernel<<<dim3(B_), dim3(H_), 0, stream>>>(xs, Wih, Whh, bia, bnp, out);
  }
}

// Round 10
// 7603.608 us; speedup vs baseline: 1.3528x; 1.3528x over previous
//
#include <hip/hip_runtime.h>
#include <stdint.h>
#include <stddef.h>

#define B_ 16
#define T_ 4096
#define D_ 256
#define H_ 512
#define G3_ 1536

// ws layout
#define OFF_IG   ((size_t)0)                       // igates f16: 65536*1536*2 = 201326592
#define OFF_WT   ((size_t)201326592)               // W_ih^T packed float4: 256*1536*4 = 1572864
#define OFF_MB   ((size_t)202899456)               // mailboxes: 2*16*8*512*4 = 524288
#define WS_NEED  ((size_t)203423744)

#define PAR_STRIDE ((size_t)B_ * 8 * 512)           // words per parity buffer

typedef _Float16 h2_t __attribute__((ext_vector_type(2)));

#if defined(__has_builtin)
#if __has_builtin(__builtin_amdgcn_fdot2)
#define HAVE_FDOT2 1
#endif
#endif

__device__ __forceinline__ float fdot2f(uint32_t w, uint32_t h, float acc) {
  union { uint32_t u; h2_t v; } a, b;
  a.u = w; b.u = h;
#ifdef HAVE_FDOT2
  return __builtin_amdgcn_fdot2(a.v, b.v, acc, false);
#else
  return fmaf((float)a.v.x, (float)b.v.x, fmaf((float)a.v.y, (float)b.v.y, acc));
#endif
}

__device__ __forceinline__ uint32_t packh2(float a, float b) {
  union { h2_t v; uint32_t u; } x;
  x.v.x = (_Float16)a; x.v.y = (_Float16)b;
  return x.u;
}

__device__ __forceinline__ uint32_t f16bits(float a) {
  union { _Float16 h; uint16_t u; } x;
  x.h = (_Float16)a;
  return (uint32_t)x.u;
}

__device__ __forceinline__ float h2f(uint16_t u) {
  union { _Float16 h; uint16_t u; } x;
  x.u = u;
  return (float)x.h;
}

__device__ __forceinline__ float sigmoidf_(float x) {
  return 1.0f / (1.0f + __expf(-x));
}

__device__ __forceinline__ float tanhf_(float x) {
  x = fminf(fmaxf(x, -15.0f), 15.0f);
  float e = __expf(-2.0f * x);
  return (1.0f - e) / (1.0f + e);
}

// ---------------- Kernel 1: transpose+pack W_ih into [d/4][g] float4 ----------------
__global__ void __launch_bounds__(256) wt_kernel(const float* __restrict__ W, float4* __restrict__ Wt4) {
  int idx = blockIdx.x * 256 + threadIdx.x;   // over 1536*64
  if (idx >= G3_ * 64) return;
  int g = idx % G3_;
  int d4 = idx / G3_;
  float4 v = *(const float4*)(W + (size_t)g * D_ + 4 * d4);
  Wt4[(size_t)d4 * G3_ + g] = v;
}

// ---------------- Kernel 2: igates = xs @ W_ih^T + b  -> f16 ----------------
__global__ void __launch_bounds__(256) ig_kernel(const float* __restrict__ xs,
                                                 const float* __restrict__ Wt,
                                                 const float* __restrict__ bias,
                                                 _Float16* __restrict__ ig) {
  __shared__ float xls[16 * 256];
  const int m0 = blockIdx.x * 16;
  const int tid = threadIdx.x;

  const float4* xsrc = (const float4*)(xs + (size_t)m0 * D_);
  float4* xdst = (float4*)xls;
#pragma unroll
  for (int k = 0; k < 4; ++k) xdst[tid + 256 * k] = xsrc[tid + 256 * k];
  __syncthreads();

  float acc[6][16];
#pragma unroll
  for (int k = 0; k < 6; ++k)
#pragma unroll
    for (int m = 0; m < 16; ++m) acc[k][m] = 0.0f;

  const float4* Wt4 = (const float4*)Wt;
  const float4* lds4 = (const float4*)xls;

  for (int d4 = 0; d4 < 64; ++d4) {
    float4 w[6];
#pragma unroll
    for (int k = 0; k < 6; ++k) w[k] = Wt4[(size_t)d4 * G3_ + tid + 256 * k];
#pragma unroll
    for (int m = 0; m < 16; ++m) {
      float4 xv = lds4[m * 64 + d4];
#pragma unroll
      for (int k = 0; k < 6; ++k) {
        acc[k][m] = fmaf(w[k].x, xv.x, acc[k][m]);
        acc[k][m] = fmaf(w[k].y, xv.y, acc[k][m]);
        acc[k][m] = fmaf(w[k].z, xv.z, acc[k][m]);
        acc[k][m] = fmaf(w[k].w, xv.w, acc[k][m]);
      }
    }
  }

#pragma unroll
  for (int k = 0; k < 6; ++k) {
    float bb = bias[tid + 256 * k];
#pragma unroll
    for (int m = 0; m < 16; ++m) {
      ig[(size_t)(m0 + m) * G3_ + tid + 256 * k] = (_Float16)(acc[k][m] + bb);
    }
  }
}

// ---------------- Kernel 3: persistent recurrence ----------------
// 128 WGs x 512 threads. WG wg: batch b = wg>>3, sub s = wg&7 owns columns
// [s*64, s*64+64). Thread: q = tid&7 (K-slice of 64), c = tid>>3 (0..63),
// j = s*64 + c. Weights: rows {j, j+512, j+1024} x K[q*64,+64) = 96 packed
// f16-pair VGPRs.
// Exchange: 8 mailbox copies per batch (512 tagged words (tag<<16)|f16(h)),
// double-buffered by parity, MALL-scope only (R9 killed L2 tricks for good).
// Producer: lane q agent-stores column j into copy q (1 store/thread).
// Consumer: WG s polls copy s; thread tid polls word tid -> EXACTLY 1 poller
// per word (R8 had 2; R7's 64 was a disaster) and no per-thread pair-jitter.
// Pipelined 2-deep poll: two dword sc1 loads in flight, s_waitcnt vmcnt(1)
// alternating -> sampling interval ~RT/2 instead of RT. sched_barrier(0)
// after each waitcnt (rule: compiler hoists register reads past asm waitcnt).
// Detection -> LDS u16 stage -> ONE barrier/step -> dot (conflict-free b128).
// Race bound: overwrite(tag t+2 in slot parity t&1) <- producer detect(t+1)
// <- all WGs publish(t+1) <- their barrier(t) <- all lanes' last reads of
// slot(t). Safe. Cross-replay: mailbox memset'd in-stream each launch.
__global__ void __launch_bounds__(512, 1) rec_kernel(const _Float16* __restrict__ ig,
                                                     const float* __restrict__ Whh,
                                                     const float* __restrict__ bn,
                                                     uint32_t* __restrict__ mb,
                                                     float* __restrict__ out) {
  const int tid = threadIdx.x;
  const int wg = blockIdx.x;       // 0..127
  const int b = wg >> 3;           // 0..15
  const int s = wg & 7;            // 0..7
  const int q = tid & 7;           // K-slice
  const int c = tid >> 3;          // 0..63
  const int j = s * 64 + c;        // 0..511

  // ---- load + pack weights into registers (96 dwords) ----
  uint32_t wr[32], wz[32], wn[32];
  {
    const float4* s0 = (const float4*)(Whh + (size_t)j * H_ + q * 64);
    const float4* s1 = (const float4*)(Whh + (size_t)(j + H_) * H_ + q * 64);
    const float4* s2 = (const float4*)(Whh + (size_t)(j + 2 * H_) * H_ + q * 64);
#pragma unroll
    for (int i = 0; i < 16; ++i) {
      float4 v0 = s0[i]; wr[2 * i] = packh2(v0.x, v0.y); wr[2 * i + 1] = packh2(v0.z, v0.w);
      float4 v1 = s1[i]; wz[2 * i] = packh2(v1.x, v1.y); wz[2 * i + 1] = packh2(v1.z, v1.w);
      float4 v2 = s2[i]; wn[2 * i] = packh2(v2.x, v2.y); wn[2 * i + 1] = packh2(v2.z, v2.w);
    }
  }
  const float bnj = bn[j];

  // double-buffered padded LDS h-pairs: [parity][8 regions][32 u32 + 4 pad]
  __shared__ uint32_t hl[2][8][36];
  uint16_t* hl16 = (uint16_t*)hl;

  // mailbox addresses
  uint32_t* mypoll = mb + ((size_t)b * 8 + s) * 512 + tid;   // copy s, word tid
  uint32_t* mypub  = mb + ((size_t)b * 8 + q) * 512 + j;     // copy q, word j

  const uint16_t* ig16 = (const uint16_t*)ig;
  size_t igbase = (size_t)b * T_ * G3_;

  // ig pipeline: cur(t), nxt(t+1) preloaded; fut(t+2) issued post-detection
  uint16_t cr = ig16[igbase + j];
  uint16_t cz = ig16[igbase + j + H_];
  uint16_t cn = ig16[igbase + j + 2 * H_];
  uint16_t nr = ig16[igbase + G3_ + j];
  uint16_t nz = ig16[igbase + G3_ + j + H_];
  uint16_t nn2 = ig16[igbase + G3_ + j + 2 * H_];

  float hprev = 0.0f;

  for (int t = 0; t < T_; ++t) {
    uint16_t fr = 0, fz = 0, fn = 0;

    if (t > 0) {
      // ---- pipelined 2-deep poll of my single word ----
      uint32_t* pb = mypoll + (size_t)(t & 1) * PAR_STRIDE;
      const uint32_t want = (uint32_t)t;
      uint32_t va, vb, a0 = 0;
      // prime two samples
      asm volatile("global_load_dword %0, %2, off sc1\n\t"
                   "global_load_dword %1, %2, off sc1"
                   : "=&v"(va), "=&v"(vb) : "v"(pb) : "memory");
      int it = 0;
      for (;;) {
        asm volatile("s_waitcnt vmcnt(1)" ::: "memory");
        __builtin_amdgcn_sched_barrier(0);
        a0 = va;
        if ((a0 >> 16) == want) break;
        asm volatile("global_load_dword %0, %1, off sc1" : "=&v"(va) : "v"(pb) : "memory");
        asm volatile("s_waitcnt vmcnt(1)" ::: "memory");
        __builtin_amdgcn_sched_barrier(0);
        a0 = vb;
        if ((a0 >> 16) == want) break;
        asm volatile("global_load_dword %0, %1, off sc1" : "=&v"(vb) : "v"(pb) : "memory");
        if (++it > (1 << 20)) { a0 = 0x7C00u; break; }   // visible poison, no hang
      }
      asm volatile("s_waitcnt vmcnt(0)" ::: "memory");    // drain leftover sample
      __builtin_amdgcn_sched_barrier(0);

      // stage my h column into LDS: word tid -> region tid>>6, offset tid&63
      hl16[(t & 1) * 576 + (tid >> 6) * 72 + (tid & 63)] = (uint16_t)(a0 & 0xFFFFu);

      // issue t+2 ig prefetch now (post-detection: polls never drain a fresh load)
      if (t + 2 < T_) {
        const size_t fb = igbase + 2 * (size_t)G3_;
        fr = ig16[fb + j];
        fz = ig16[fb + j + H_];
        fn = ig16[fb + j + 2 * H_];
      }
    } else {
      const size_t fb = igbase + 2 * (size_t)G3_;
      fr = ig16[fb + j];
      fz = ig16[fb + j + H_];
      fn = ig16[fb + j + 2 * H_];
    }

    __syncthreads();   // single barrier per step (double-buffered hl)

    float ar = 0.0f, az = 0.0f, an = 0.0f;
    if (t > 0) {
      // ---- dot: 3 gates x 32 fdot2, 2 chains per gate; conflict-free b128 ----
      const uint4* hq = (const uint4*)hl[t & 1][q];
      uint4 hv[8];
#pragma unroll
      for (int i = 0; i < 8; ++i) hv[i] = hq[i];
      float ar0 = 0.0f, az0 = 0.0f, an0 = 0.0f;
      float ar1 = 0.0f, az1 = 0.0f, an1 = 0.0f;
#pragma unroll
      for (int i = 0; i < 4; ++i) {
        ar0 = fdot2f(wr[4 * i + 0], hv[i].x, ar0); az0 = fdot2f(wz[4 * i + 0], hv[i].x, az0); an0 = fdot2f(wn[4 * i + 0], hv[i].x, an0);
        ar0 = fdot2f(wr[4 * i + 1], hv[i].y, ar0); az0 = fdot2f(wz[4 * i + 1], hv[i].y, az0); an0 = fdot2f(wn[4 * i + 1], hv[i].y, an0);
        ar0 = fdot2f(wr[4 * i + 2], hv[i].z, ar0); az0 = fdot2f(wz[4 * i + 2], hv[i].z, az0); an0 = fdot2f(wn[4 * i + 2], hv[i].z, an0);
        ar0 = fdot2f(wr[4 * i + 3], hv[i].w, ar0); az0 = fdot2f(wz[4 * i + 3], hv[i].w, az0); an0 = fdot2f(wn[4 * i + 3], hv[i].w, an0);
      }
#pragma unroll
      for (int i = 4; i < 8; ++i) {
        ar1 = fdot2f(wr[4 * i + 0], hv[i].x, ar1); az1 = fdot2f(wz[4 * i + 0], hv[i].x, az1); an1 = fdot2f(wn[4 * i + 0], hv[i].x, an1);
        ar1 = fdot2f(wr[4 * i + 1], hv[i].y, ar1); az1 = fdot2f(wz[4 * i + 1], hv[i].y, az1); an1 = fdot2f(wn[4 * i + 1], hv[i].y, an1);
        ar1 = fdot2f(wr[4 * i + 2], hv[i].z, ar1); az1 = fdot2f(wz[4 * i + 2], hv[i].z, az1); an1 = fdot2f(wn[4 * i + 2], hv[i].z, an1);
        ar1 = fdot2f(wr[4 * i + 3], hv[i].w, ar1); az1 = fdot2f(wz[4 * i + 3], hv[i].w, az1); an1 = fdot2f(wn[4 * i + 3], hv[i].w, an1);
      }
      ar = ar0 + ar1; az = az0 + az1; an = an0 + an1;
      // reduce across the 8 K-slice lanes (lanes 8c..8c+7)
      ar += __shfl_xor(ar, 1); ar += __shfl_xor(ar, 2); ar += __shfl_xor(ar, 4);
      az += __shfl_xor(az, 1); az += __shfl_xor(az, 2); az += __shfl_xor(az, 4);
      an += __shfl_xor(an, 1); an += __shfl_xor(an, 2); an += __shfl_xor(an, 4);
    }

    // ---- gates (redundant on all 8 q-lanes of a column) ----
    const float igr = h2f(cr), igz = h2f(cz), ign = h2f(cn);
    const float r = sigmoidf_(igr + ar);
    const float z = sigmoidf_(igz + az);
    const float n = tanhf_(ign + r * (an + bnj));
    const float hnew = n + z * (hprev - n);
    hprev = hnew;

    // ---- publish: 1 tagged agent store per thread (lane q -> copy q) ----
    const uint32_t wv = ((uint32_t)(t + 1) << 16) | f16bits(hnew);
    __hip_atomic_store(mypub + (size_t)((t + 1) & 1) * PAR_STRIDE, wv,
                       __ATOMIC_RELAXED, __HIP_MEMORY_SCOPE_AGENT);

    if (q == 0) {
      out[((size_t)b * T_ + t) * H_ + j] = hnew;
    }

    // rotate ig pipeline
    cr = nr; cz = nz; cn = nn2;
    nr = fr; nz = fz; nn2 = fn;
    igbase += G3_;
  }
}

// ---------------- Fallback: naive (only if ws too small) ----------------
__global__ void __launch_bounds__(512) naive_kernel(const float* __restrict__ xs,
                                                    const float* __restrict__ Wih,
                                                    const float* __restrict__ Whh,
                                                    const float* __restrict__ bias,
                                                    const float* __restrict__ bn,
                                                    float* __restrict__ out) {
  const int b = blockIdx.x;
  const int j = threadIdx.x;
  __shared__ float h[H_];
  __shared__ float xr[D_];
  h[j] = 0.0f;
  __syncthreads();
  for (int t = 0; t < T_; ++t) {
    if (j < D_) xr[j] = xs[((size_t)b * T_ + t) * D_ + j];
    __syncthreads();
    float a[2];
#pragma unroll
    for (int g = 0; g < 2; ++g) {
      const int row = j + g * H_;
      float ssum = bias[row];
      const float* wi = Wih + (size_t)row * D_;
      for (int d = 0; d < D_; ++d) ssum = fmaf(wi[d], xr[d], ssum);
      const float* wh = Whh + (size_t)row * H_;
      for (int kk = 0; kk < H_; ++kk) ssum = fmaf(wh[kk], h[kk], ssum);
      a[g] = ssum;
    }
    const float r = sigmoidf_(a[0]);
    const float z = sigmoidf_(a[1]);
    float i_n = bias[j + 2 * H_];
    {
      const float* wi = Wih + (size_t)(j + 2 * H_) * D_;
      for (int d = 0; d < D_; ++d) i_n = fmaf(wi[d], xr[d], i_n);
    }
    float h_n = 0.0f;
    {
      const float* wh = Whh + (size_t)(j + 2 * H_) * H_;
      for (int kk = 0; kk < H_; ++kk) h_n = fmaf(wh[kk], h[kk], h_n);
    }
    const float nn = tanhf_(i_n + r * (h_n + bn[j]));
    const float hnew = nn + z * (h[j] - nn);
    __syncthreads();
    h[j] = hnew;
    out[((size_t)b * T_ + t) * H_ + j] = hnew;
  }
}

extern "C" void kernel_launch(void* const* d_in, const int* in_sizes, int n_in,
                              void* d_out, int out_size, void* d_ws, size_t ws_size,
                              hipStream_t stream) {
  const float* xs  = (const float*)d_in[0];
  const float* Wih = (const float*)d_in[1];
  const float* Whh = (const float*)d_in[2];
  const float* bia = (const float*)d_in[3];
  const float* bnp = (const float*)d_in[4];
  float* out = (float*)d_out;

  if (ws_size >= WS_NEED) {
    char* ws = (char*)d_ws;
    _Float16* igp = (_Float16*)(ws + OFF_IG);
    float* wtp = (float*)(ws + OFF_WT);
    uint32_t* mbp = (uint32_t*)(ws + OFF_MB);

    // zero tag mailboxes (stale-tag kill across graph replays)
    hipMemsetAsync(mbp, 0, 2 * PAR_STRIDE * sizeof(uint32_t), stream);

    wt_kernel<<<dim3(384), dim3(256), 0, stream>>>(Wih, (float4*)wtp);
    ig_kernel<<<dim3((B_ * T_) / 16), dim3(256), 0, stream>>>(xs, wtp, bia, igp);
    rec_kernel<<<dim3(128), dim3(512), 0, stream>>>(igp, Whh, bnp, mbp, out);
  } else {
    naive_kernel<<<dim3(B_), dim3(H_), 0, stream>>>(xs, Wih, Whh, bia, bnp, out);
  }
}

// Round 11
// 7268.927 us; speedup vs baseline: 1.4150x; 1.0460x over previous
//
#include <hip/hip_runtime.h>
#include <stdint.h>
#include <stddef.h>

#define B_ 16
#define T_ 4096
#define D_ 256
#define H_ 512
#define G3_ 1536

// ws layout
#define OFF_IG   ((size_t)0)                       // igates f16: 65536*1536*2 = 201326592
#define OFF_WT   ((size_t)201326592)               // W_ih^T packed float4: 256*1536*4 = 1572864
#define OFF_MB   ((size_t)202899456)               // mailboxes: 2*16*8*512*4 = 524288
#define WS_NEED  ((size_t)203423744)

#define PAR_STRIDE ((size_t)B_ * 8 * 512)           // words per parity buffer

typedef _Float16 h2_t __attribute__((ext_vector_type(2)));

#if defined(__has_builtin)
#if __has_builtin(__builtin_amdgcn_fdot2)
#define HAVE_FDOT2 1
#endif
#endif

__device__ __forceinline__ float fdot2f(uint32_t w, uint32_t h, float acc) {
  union { uint32_t u; h2_t v; } a, b;
  a.u = w; b.u = h;
#ifdef HAVE_FDOT2
  return __builtin_amdgcn_fdot2(a.v, b.v, acc, false);
#else
  return fmaf((float)a.v.x, (float)b.v.x, fmaf((float)a.v.y, (float)b.v.y, acc));
#endif
}

__device__ __forceinline__ uint32_t packh2(float a, float b) {
  union { h2_t v; uint32_t u; } x;
  x.v.x = (_Float16)a; x.v.y = (_Float16)b;
  return x.u;
}

__device__ __forceinline__ uint32_t f16bits(float a) {
  union { _Float16 h; uint16_t u; } x;
  x.h = (_Float16)a;
  return (uint32_t)x.u;
}

__device__ __forceinline__ float h2f(uint16_t u) {
  union { _Float16 h; uint16_t u; } x;
  x.u = u;
  return (float)x.h;
}

__device__ __forceinline__ float sigmoidf_(float x) {
  return 1.0f / (1.0f + __expf(-x));
}

__device__ __forceinline__ float tanhf_(float x) {
  x = fminf(fmaxf(x, -15.0f), 15.0f);
  float e = __expf(-2.0f * x);
  return (1.0f - e) / (1.0f + e);
}

// ---------------- Kernel 1: transpose+pack W_ih into [d/4][g] float4 ----------------
__global__ void __launch_bounds__(256) wt_kernel(const float* __restrict__ W, float4* __restrict__ Wt4) {
  int idx = blockIdx.x * 256 + threadIdx.x;   // over 1536*64
  if (idx >= G3_ * 64) return;
  int g = idx % G3_;
  int d4 = idx / G3_;
  float4 v = *(const float4*)(W + (size_t)g * D_ + 4 * d4);
  Wt4[(size_t)d4 * G3_ + g] = v;
}

// ---------------- Kernel 2: igates = xs @ W_ih^T + b  -> f16 ----------------
__global__ void __launch_bounds__(256) ig_kernel(const float* __restrict__ xs,
                                                 const float* __restrict__ Wt,
                                                 const float* __restrict__ bias,
                                                 _Float16* __restrict__ ig) {
  __shared__ float xls[16 * 256];
  const int m0 = blockIdx.x * 16;
  const int tid = threadIdx.x;

  const float4* xsrc = (const float4*)(xs + (size_t)m0 * D_);
  float4* xdst = (float4*)xls;
#pragma unroll
  for (int k = 0; k < 4; ++k) xdst[tid + 256 * k] = xsrc[tid + 256 * k];
  __syncthreads();

  float acc[6][16];
#pragma unroll
  for (int k = 0; k < 6; ++k)
#pragma unroll
    for (int m = 0; m < 16; ++m) acc[k][m] = 0.0f;

  const float4* Wt4 = (const float4*)Wt;
  const float4* lds4 = (const float4*)xls;

  for (int d4 = 0; d4 < 64; ++d4) {
    float4 w[6];
#pragma unroll
    for (int k = 0; k < 6; ++k) w[k] = Wt4[(size_t)d4 * G3_ + tid + 256 * k];
#pragma unroll
    for (int m = 0; m < 16; ++m) {
      float4 xv = lds4[m * 64 + d4];
#pragma unroll
      for (int k = 0; k < 6; ++k) {
        acc[k][m] = fmaf(w[k].x, xv.x, acc[k][m]);
        acc[k][m] = fmaf(w[k].y, xv.y, acc[k][m]);
        acc[k][m] = fmaf(w[k].z, xv.z, acc[k][m]);
        acc[k][m] = fmaf(w[k].w, xv.w, acc[k][m]);
      }
    }
  }

#pragma unroll
  for (int k = 0; k < 6; ++k) {
    float bb = bias[tid + 256 * k];
#pragma unroll
    for (int m = 0; m < 16; ++m) {
      ig[(size_t)(m0 + m) * G3_ + tid + 256 * k] = (_Float16)(acc[k][m] + bb);
    }
  }
}

// ---------------- Kernel 3: persistent recurrence ----------------
// 128 WGs x 512 threads. WG wg: batch b = wg>>3, sub s = wg&7 owns columns
// [s*64, s*64+64). Thread: q = tid&7 (K-slice of 64), c = tid>>3 (0..63),
// j = s*64 + c. Weights: rows {j, j+512, j+1024} x K[q*64,+64) = 96 packed
// f16-pair VGPRs.
// Exchange: 8 mailbox copies per batch (512 tagged words (tag<<16)|f16(h)),
// double-buffered by parity, MALL/agent scope. Producer: lane q agent-stores
// column j into copy q. Consumer: WG s polls copy s, thread tid -> word tid
// (1 poller/word). Pipelined 2-deep dword sc1 poll, vmcnt(1) alternating.
// COUNTER HYGIENE (R11): (a) ig prefetch 3-deep -> ig loads are a full step
// old at the next poll, never inside the poll's vmcnt; (b) vmcnt(0) drain
// after publish+out stores (overlaps the MALL propagation consumers need
// anyway) -> the poll counts ONLY its own two samples.
// Detection -> LDS u16 stage -> ONE barrier/step -> dot (conflict-free b128).
// Race bound: overwrite(tag t+2, parity t&1) <- producer detect(t+1) <- all
// WGs publish(t+1) <- their barrier(t) <- all lanes' reads of slot(t). Safe.
// Cross-replay: mailbox memset'd in-stream each launch.
__global__ void __launch_bounds__(512, 1) rec_kernel(const _Float16* __restrict__ ig,
                                                     const float* __restrict__ Whh,
                                                     const float* __restrict__ bn,
                                                     uint32_t* __restrict__ mb,
                                                     float* __restrict__ out) {
  const int tid = threadIdx.x;
  const int wg = blockIdx.x;       // 0..127
  const int b = wg >> 3;           // 0..15
  const int s = wg & 7;            // 0..7
  const int q = tid & 7;           // K-slice
  const int c = tid >> 3;          // 0..63
  const int j = s * 64 + c;        // 0..511

  // ---- load + pack weights into registers (96 dwords) ----
  uint32_t wr[32], wz[32], wn[32];
  {
    const float4* s0 = (const float4*)(Whh + (size_t)j * H_ + q * 64);
    const float4* s1 = (const float4*)(Whh + (size_t)(j + H_) * H_ + q * 64);
    const float4* s2 = (const float4*)(Whh + (size_t)(j + 2 * H_) * H_ + q * 64);
#pragma unroll
    for (int i = 0; i < 16; ++i) {
      float4 v0 = s0[i]; wr[2 * i] = packh2(v0.x, v0.y); wr[2 * i + 1] = packh2(v0.z, v0.w);
      float4 v1 = s1[i]; wz[2 * i] = packh2(v1.x, v1.y); wz[2 * i + 1] = packh2(v1.z, v1.w);
      float4 v2 = s2[i]; wn[2 * i] = packh2(v2.x, v2.y); wn[2 * i + 1] = packh2(v2.z, v2.w);
    }
  }
  const float bnj = bn[j];

  // double-buffered padded LDS h-pairs: [parity][8 regions][32 u32 + 4 pad]
  __shared__ uint32_t hl[2][8][36];
  uint16_t* hl16 = (uint16_t*)hl;

  // mailbox addresses
  uint32_t* mypoll = mb + ((size_t)b * 8 + s) * 512 + tid;   // copy s, word tid
  uint32_t* mypub  = mb + ((size_t)b * 8 + q) * 512 + j;     // copy q, word j

  const uint16_t* ig16 = (const uint16_t*)ig;
  size_t igbase = (size_t)b * T_ * G3_;

  // ig pipeline, 3-deep: cur(t), n1(t+1), n2(t+2); t+3 issued post-detection
  uint16_t cr = ig16[igbase + j];
  uint16_t cz = ig16[igbase + j + H_];
  uint16_t cn = ig16[igbase + j + 2 * H_];
  uint16_t r1 = ig16[igbase + G3_ + j];
  uint16_t z1 = ig16[igbase + G3_ + j + H_];
  uint16_t n1 = ig16[igbase + G3_ + j + 2 * H_];
  uint16_t r2 = ig16[igbase + 2 * (size_t)G3_ + j];
  uint16_t z2 = ig16[igbase + 2 * (size_t)G3_ + j + H_];
  uint16_t n2 = ig16[igbase + 2 * (size_t)G3_ + j + 2 * H_];

  float hprev = 0.0f;

  for (int t = 0; t < T_; ++t) {
    uint16_t fr = 0, fz = 0, fn = 0;

    if (t > 0) {
      // ---- pipelined 2-deep poll; vmcnt counts ONLY these two loads ----
      uint32_t* pb = mypoll + (size_t)(t & 1) * PAR_STRIDE;
      const uint32_t want = (uint32_t)t;
      uint32_t va, vb, a0 = 0;
      asm volatile("global_load_dword %0, %2, off sc1\n\t"
                   "global_load_dword %1, %2, off sc1"
                   : "=&v"(va), "=&v"(vb) : "v"(pb) : "memory");
      int it = 0;
      for (;;) {
        asm volatile("s_waitcnt vmcnt(1)" ::: "memory");
        __builtin_amdgcn_sched_barrier(0);
        a0 = va;
        if ((a0 >> 16) == want) break;
        asm volatile("global_load_dword %0, %1, off sc1" : "=&v"(va) : "v"(pb) : "memory");
        asm volatile("s_waitcnt vmcnt(1)" ::: "memory");
        __builtin_amdgcn_sched_barrier(0);
        a0 = vb;
        if ((a0 >> 16) == want) break;
        asm volatile("global_load_dword %0, %1, off sc1" : "=&v"(vb) : "v"(pb) : "memory");
        if (++it > (1 << 20)) { a0 = 0x7C00u; break; }   // visible poison, no hang
      }
      asm volatile("s_waitcnt vmcnt(0)" ::: "memory");    // drain leftover sample
      __builtin_amdgcn_sched_barrier(0);

      // stage my h column into LDS: word tid -> region tid>>6, offset tid&63
      hl16[(t & 1) * 576 + (tid >> 6) * 72 + (tid & 63)] = (uint16_t)(a0 & 0xFFFFu);
    }

    // issue t+3 ig prefetch (a full step before any waitcnt can touch it)
    if (t + 3 < T_) {
      const size_t fb = igbase + 3 * (size_t)G3_;
      fr = ig16[fb + j];
      fz = ig16[fb + j + H_];
      fn = ig16[fb + j + 2 * H_];
    }

    __syncthreads();   // single barrier per step (double-buffered hl)

    float ar = 0.0f, az = 0.0f, an = 0.0f;
    if (t > 0) {
      // ---- dot: 3 gates x 32 fdot2, 2 chains per gate; conflict-free b128 ----
      const uint4* hq = (const uint4*)hl[t & 1][q];
      uint4 hv[8];
#pragma unroll
      for (int i = 0; i < 8; ++i) hv[i] = hq[i];
      float ar0 = 0.0f, az0 = 0.0f, an0 = 0.0f;
      float ar1 = 0.0f, az1 = 0.0f, an1 = 0.0f;
#pragma unroll
      for (int i = 0; i < 4; ++i) {
        ar0 = fdot2f(wr[4 * i + 0], hv[i].x, ar0); az0 = fdot2f(wz[4 * i + 0], hv[i].x, az0); an0 = fdot2f(wn[4 * i + 0], hv[i].x, an0);
        ar0 = fdot2f(wr[4 * i + 1], hv[i].y, ar0); az0 = fdot2f(wz[4 * i + 1], hv[i].y, az0); an0 = fdot2f(wn[4 * i + 1], hv[i].y, an0);
        ar0 = fdot2f(wr[4 * i + 2], hv[i].z, ar0); az0 = fdot2f(wz[4 * i + 2], hv[i].z, az0); an0 = fdot2f(wn[4 * i + 2], hv[i].z, an0);
        ar0 = fdot2f(wr[4 * i + 3], hv[i].w, ar0); az0 = fdot2f(wz[4 * i + 3], hv[i].w, az0); an0 = fdot2f(wn[4 * i + 3], hv[i].w, an0);
      }
#pragma unroll
      for (int i = 4; i < 8; ++i) {
        ar1 = fdot2f(wr[4 * i + 0], hv[i].x, ar1); az1 = fdot2f(wz[4 * i + 0], hv[i].x, az1); an1 = fdot2f(wn[4 * i + 0], hv[i].x, an1);
        ar1 = fdot2f(wr[4 * i + 1], hv[i].y, ar1); az1 = fdot2f(wz[4 * i + 1], hv[i].y, az1); an1 = fdot2f(wn[4 * i + 1], hv[i].y, an1);
        ar1 = fdot2f(wr[4 * i + 2], hv[i].z, ar1); az1 = fdot2f(wz[4 * i + 2], hv[i].z, az1); an1 = fdot2f(wn[4 * i + 2], hv[i].z, an1);
        ar1 = fdot2f(wr[4 * i + 3], hv[i].w, ar1); az1 = fdot2f(wz[4 * i + 3], hv[i].w, az1); an1 = fdot2f(wn[4 * i + 3], hv[i].w, an1);
      }
      ar = ar0 + ar1; az = az0 + az1; an = an0 + an1;
      // reduce across the 8 K-slice lanes (lanes 8c..8c+7)
      ar += __shfl_xor(ar, 1); ar += __shfl_xor(ar, 2); ar += __shfl_xor(ar, 4);
      az += __shfl_xor(az, 1); az += __shfl_xor(az, 2); az += __shfl_xor(az, 4);
      an += __shfl_xor(an, 1); an += __shfl_xor(an, 2); an += __shfl_xor(an, 4);
    }

    // ---- gates (redundant on all 8 q-lanes of a column) ----
    const float igr = h2f(cr), igz = h2f(cz), ign = h2f(cn);
    const float r = sigmoidf_(igr + ar);
    const float z = sigmoidf_(igz + az);
    const float n = tanhf_(ign + r * (an + bnj));
    const float hnew = n + z * (hprev - n);
    hprev = hnew;

    // ---- publish + out, then drain stores (overlaps MALL propagation) ----
    const uint32_t wv = ((uint32_t)(t + 1) << 16) | f16bits(hnew);
    __hip_atomic_store(mypub + (size_t)((t + 1) & 1) * PAR_STRIDE, wv,
                       __ATOMIC_RELAXED, __HIP_MEMORY_SCOPE_AGENT);
    if (q == 0) {
      out[((size_t)b * T_ + t) * H_ + j] = hnew;
    }
    asm volatile("s_waitcnt vmcnt(0)" ::: "memory");
    __builtin_amdgcn_sched_barrier(0);

    // rotate ig pipeline
    cr = r1; cz = z1; cn = n1;
    r1 = r2; z1 = z2; n1 = n2;
    r2 = fr; z2 = fz; n2 = fn;
    igbase += G3_;
  }
}

// ---------------- Fallback: naive (only if ws too small) ----------------
__global__ void __launch_bounds__(512) naive_kernel(const float* __restrict__ xs,
                                                    const float* __restrict__ Wih,
                                                    const float* __restrict__ Whh,
                                                    const float* __restrict__ bias,
                                                    const float* __restrict__ bn,
                                                    float* __restrict__ out) {
  const int b = blockIdx.x;
  const int j = threadIdx.x;
  __shared__ float h[H_];
  __shared__ float xr[D_];
  h[j] = 0.0f;
  __syncthreads();
  for (int t = 0; t < T_; ++t) {
    if (j < D_) xr[j] = xs[((size_t)b * T_ + t) * D_ + j];
    __syncthreads();
    float a[2];
#pragma unroll
    for (int g = 0; g < 2; ++g) {
      const int row = j + g * H_;
      float ssum = bias[row];
      const float* wi = Wih + (size_t)row * D_;
      for (int d = 0; d < D_; ++d) ssum = fmaf(wi[d], xr[d], ssum);
      const float* wh = Whh + (size_t)row * H_;
      for (int kk = 0; kk < H_; ++kk) ssum = fmaf(wh[kk], h[kk], ssum);
      a[g] = ssum;
    }
    const float r = sigmoidf_(a[0]);
    const float z = sigmoidf_(a[1]);
    float i_n = bias[j + 2 * H_];
    {
      const float* wi = Wih + (size_t)(j + 2 * H_) * D_;
      for (int d = 0; d < D_; ++d) i_n = fmaf(wi[d], xr[d], i_n);
    }
    float h_n = 0.0f;
    {
      const float* wh = Whh + (size_t)(j + 2 * H_) * H_;
      for (int kk = 0; kk < H_; ++kk) h_n = fmaf(wh[kk], h[kk], h_n);
    }
    const float nn = tanhf_(i_n + r * (h_n + bn[j]));
    const float hnew = nn + z * (h[j] - nn);
    __syncthreads();
    h[j] = hnew;
    out[((size_t)b * T_ + t) * H_ + j] = hnew;
  }
}

extern "C" void kernel_launch(void* const* d_in, const int* in_sizes, int n_in,
                              void* d_out, int out_size, void* d_ws, size_t ws_size,
                              hipStream_t stream) {
  const float* xs  = (const float*)d_in[0];
  const float* Wih = (const float*)d_in[1];
  const float* Whh = (const float*)d_in[2];
  const float* bia = (const float*)d_in[3];
  const float* bnp = (const float*)d_in[4];
  float* out = (float*)d_out;

  if (ws_size >= WS_NEED) {
    char* ws = (char*)d_ws;
    _Float16* igp = (_Float16*)(ws + OFF_IG);
    float* wtp = (float*)(ws + OFF_WT);
    uint32_t* mbp = (uint32_t*)(ws + OFF_MB);

    // zero tag mailboxes (stale-tag kill across graph replays)
    hipMemsetAsync(mbp, 0, 2 * PAR_STRIDE * sizeof(uint32_t), stream);

    wt_kernel<<<dim3(384), dim3(256), 0, stream>>>(Wih, (float4*)wtp);
    ig_kernel<<<dim3((B_ * T_) / 16), dim3(256), 0, stream>>>(xs, wtp, bia, igp);
    rec_kernel<<<dim3(128), dim3(512), 0, stream>>>(igp, Whh, bnp, mbp, out);
  } else {
    naive_kernel<<<dim3(B_), dim3(H_), 0, stream>>>(xs, Wih, Whh, bia, bnp, out);
  }
}